// Round 9
// baseline (245.251 us; speedup 1.0000x reference)
//
#include <hip/hip_runtime.h>
#include <math.h>

#define Bn 4
#define Cn 256
#define Hn 64
#define Wn 64
#define On 256
#define HWn 4096
#define Pn 16384   // B*H*W
#define Kc 2304    // 9*256

// s_waitcnt imm: vmcnt=63 (no wait), expcnt=7 (no wait), lgkmcnt=0 (drain LDS)
#define LGKM0 0xc07f

typedef _Float16 half8 __attribute__((ext_vector_type(8)));
typedef float floatx4 __attribute__((ext_vector_type(4)));

// ---------------------------------------------------------------------------
// R16 init kernel (unchanged from R8; layouts bit-identical):
//  blocks 0..1023: fp32 NCHW -> f16 NHWC transpose (float4 reads, LDS, half8
//  writes); 1024..1791: main-weight pack (half8 stores);
//  1792..1887: offset-weight pack (channel-group-major chunk order).
__global__ void k_init(const float* __restrict__ x, _Float16* __restrict__ act0,
                       const float* __restrict__ w0, const float* __restrict__ w1,
                       const float* __restrict__ w2, const float* __restrict__ wo0,
                       const float* __restrict__ wo1, const float* __restrict__ wo2,
                       _Float16* __restrict__ wtp, _Float16* __restrict__ wbop) {
  int bx = blockIdx.x;
  int tid = threadIdx.x;   // 0..255
  if (bx < 1024) {
    __shared__ float Tf[64][65];
    int b = bx >> 8;
    int c0 = ((bx >> 6) & 3) << 6;
    int hw0 = (bx & 63) << 6;
    const float* ib = x + ((size_t)b * Cn + c0) * HWn + hw0;
    _Float16* ob = act0 + ((size_t)b * HWn + hw0) * Cn + c0;
    int ty = tid >> 4, tx = tid & 15;
#pragma unroll
    for (int p = 0; p < 4; ++p) {
      int ch = p * 16 + ty;
      float4 v = *(const float4*)(ib + (size_t)ch * HWn + tx * 4);
      Tf[ch][tx * 4 + 0] = v.x;
      Tf[ch][tx * 4 + 1] = v.y;
      Tf[ch][tx * 4 + 2] = v.z;
      Tf[ch][tx * 4 + 3] = v.w;
    }
    __syncthreads();
    int hwR = tid >> 3, seg = tid & 7;
#pragma unroll
    for (int p = 0; p < 2; ++p) {
      int hw = p * 32 + hwR;
      half8 h;
#pragma unroll
      for (int k = 0; k < 8; ++k) h[k] = (_Float16)Tf[seg * 8 + k][hw];
      *(half8*)(ob + (size_t)hw * Cn + seg * 8) = h;
    }
  } else if (bx < 1792) {
    int b2 = bx - 1024;
    int l = b2 >> 8;
    int n = b2 & 255;
    const float* w = (l == 0) ? w0 : (l == 1) ? w1 : w2;
    _Float16* dst = wtp + (size_t)l * 256 * Kc;
    int g = n >> 4, col = n & 15;
#pragma unroll
    for (int e2 = tid; e2 < 288; e2 += 256) {
      int c = e2 >> 3;          // 0..35
      int r = e2 & 7;
      int kq = r >> 2;
      int quad = r & 3;
      int t = c >> 2;
      int cq = c & 3;
      const float* s = w + (size_t)n * 2304 + (size_t)(cq * 64 + kq * 32 + quad * 8) * 9 + t;
      half8 h;
#pragma unroll
      for (int e = 0; e < 8; ++e) h[e] = (_Float16)s[e * 9];
      *(half8*)(dst + ((size_t)((c * 16 + g) * 2 + kq)) * 512 + (quad * 16 + col) * 8) = h;
    }
  } else {
    int b3 = bx - 1792;
    int l = b3 >> 5;
    int n = b3 & 31;
    const float* w = (l == 0) ? wo0 : (l == 1) ? wo1 : wo2;
    _Float16* dst = wbop + (size_t)l * 36 * 2048;
    int g = n >> 4, col = n & 15;
#pragma unroll
    for (int e2 = tid; e2 < 288; e2 += 256) {
      int c = e2 >> 3;
      int r = e2 & 7;
      int kq = r >> 2;
      int quad = r & 3;
      int cw = c / 9;
      int t = c - cw * 9;
      half8 h;
      if (n < 27) {
        const float* s = w + ((size_t)n * 256 + cw * 64 + kq * 32 + quad * 8) * 9 + t;
#pragma unroll
        for (int e = 0; e < 8; ++e) h[e] = (_Float16)s[e * 9];
      } else {
#pragma unroll
        for (int e = 0; e < 8; ++e) h[e] = (_Float16)0.f;
      }
      *(half8*)(dst + ((size_t)((c * 2 + g) * 2 + kq)) * 512 + (quad * 16 + col) * 8) = h;
    }
  }
}

// ---------------------------------------------------------------------------
// R17 layer kernel: M=32 px/block (half image row), grid=512, 512 threads,
// LDS ~36KB -> TWO CO-RESIDENT BLOCKS PER CU (independent barrier domains).
// Diagnosis: every prior config was 1 block/CU; all waves shared one barrier,
// so every vmcnt/barrier drain idled the whole CU (m114 pathology). R4 added
// waves in the SAME domain (null). Two domains let block B issue while block
// A drains.
// Phase 1: R6 LDS-window offset conv (3x34 window, compute waves 0-3).
// Phase 2: reg-B N-split (R5, zero B duplication), depth-2 parity slots
//   refilled AFTER the MFMA cluster (WAR-safe, 2-chunk slack); gather role
//   tid<256 (32 rows x 8 segs). XCD swizzle for nwg=512.
__global__ __launch_bounds__(512, 4) void k_layer(
    const _Float16* __restrict__ xh,
    const _Float16* __restrict__ wbop, const float* __restrict__ boff,
    const _Float16* __restrict__ wtp, const float* __restrict__ bias,
    _Float16* __restrict__ outh, float* __restrict__ outf) {
  __shared__ __align__(16) _Float16 As[2][32][72];    // 9.2 KB
  __shared__ __align__(16) _Float16 win[3 * 34 * 64]; // 13.1 KB
  __shared__ __align__(16) float omS[32 * 33];        // 4.2 KB
  __shared__ __align__(16) float sampS[32][9][8];     // 9 KB

  int bid = blockIdx.x;
  int lb = ((bid & 7) << 6) + (bid >> 3);   // bijective XCD swizzle, nwg=512
  int p0 = lb * 32;                          // 32-pixel half-row tile
  int tid = threadIdx.x;       // 0..511
  int lane = tid & 63;
  int wave = tid >> 6;         // 0..7
  int quad = lane >> 4;
  int col = lane & 15;

  bool gth = tid < 256;        // gather/A-staging role
  int ar = (tid & 255) >> 3;   // row 0..31
  int aci = (tid & 7) * 8;     // 8-channel segment

  int yB = (p0 & 4095) >> 6;   // block-uniform image row
  int bB = p0 >> 12;
  int x0B = p0 & 63;           // 0 or 32

  half8 zero8;
#pragma unroll
  for (int e = 0; e < 8; ++e) zero8[e] = (_Float16)0.f;

  // ================= phase 1: offset conv (M=32,N=32,K=2304) =============
  // compute on waves 0-3: mi = wave>>1 (16-row group), ng = wave&1.
  int mi = (wave >> 1) & 1;
  int ng = wave & 1;
  bool p1c = wave < 4;

  floatx4 acc1 = (floatx4){0.f, 0.f, 0.f, 0.f};
  half8 boA[2], boB[2];
  if (p1c) {
#pragma unroll
    for (int kq = 0; kq < 2; ++kq) {
      boA[kq] = *(const half8*)(wbop + (size_t)(ng * 2 + kq) * 512 + lane * 8);
      boB[kq] = *(const half8*)(wbop + 2048 + (size_t)(ng * 2 + kq) * 512 + lane * 8);
    }
  }

#pragma unroll 1
  for (int cg = 0; cg < 4; ++cg) {
    // stage window: 3 rows x 34 px x 8 segs = 816 half8 slots
    for (int e = tid; e < 816; e += 512) {
      int seg = e & 7;
      int rowpx = e >> 3;          // 0..101
      int r = rowpx / 34;          // 0..2
      int px = rowpx - r * 34;     // 0..33
      int yy = yB + r - 1;
      int xx = x0B + px - 1;
      half8 v = zero8;
      if (((unsigned)yy < 64u) & ((unsigned)xx < 64u))
        v = *(const half8*)(xh + ((size_t)((bB * Hn + yy) * Wn + xx)) * Cn +
                            cg * 64 + seg * 8);
      int ba = (rowpx * 128 + seg * 16) ^ ((px & 7) << 4);
      *(half8*)((char*)win + ba) = v;
    }
    __syncthreads();

#pragma unroll
    for (int t = 0; t < 9; ++t) {
      int cp = cg * 9 + t;
      if (p1c) {
        int dty = t / 3;
        int dtx = t % 3;
#pragma unroll
        for (int kq = 0; kq < 2; ++kq) {
          int pxw = mi * 16 + col + dtx;   // 0..33
          int ba = ((dty * 34 + pxw) * 128 + kq * 64 + quad * 16) ^ ((pxw & 7) << 4);
          half8 af = *(const half8*)((const char*)win + ba);
          acc1 = __builtin_amdgcn_mfma_f32_16x16x32_f16(
              af, (cp & 1) ? boB[kq] : boA[kq], acc1, 0, 0, 0);
        }
        if (cp + 2 < 36) {
          const _Float16* wob = wbop + (size_t)(cp + 2) * 2048;
#pragma unroll
          for (int kq = 0; kq < 2; ++kq) {
            half8 v2 = *(const half8*)(wob + (size_t)(ng * 2 + kq) * 512 + lane * 8);
            if (cp & 1) boB[kq] = v2; else boA[kq] = v2;
          }
        }
      }
    }
    __syncthreads();   // before next cg overwrites win
  }

  // om -> LDS (rows 0..31)
  if (p1c) {
    int n1 = ng * 16 + col;
    if (n1 < 27) {
      float bb = boff[n1];
#pragma unroll
      for (int r = 0; r < 4; ++r)
        omS[(mi * 16 + quad * 4 + r) * 33 + n1] = acc1[r] + bb;
    }
  }
  __syncthreads();

  // fused coords: 32 px x 9 taps = 288 entries -> sampS
  if (tid < 288) {
    int e = tid;
    int lp = e / 9;
    int k = e - lp * 9;
    int pp = p0 + lp;
    int bi = pp >> 12;
    int pyx = pp & 4095;
    int py = pyx >> 6, px = pyx & 63;

    float dy = omS[lp * 33 + 2 * k];
    float dx = omS[lp * 33 + 2 * k + 1];
    float m = 1.f / (1.f + expf(-omS[lp * 33 + 18 + k]));

    float ys = (float)(py + k / 3 - 1) + dy;
    float xs = (float)(px + k % 3 - 1) + dx;
    float y0f = floorf(ys), x0f = floorf(xs);
    float wy = ys - y0f, wx = xs - x0f;
    int y0 = (int)y0f, x0 = (int)x0f;
    int y1 = y0 + 1, x1 = x0 + 1;

    bool vy0 = (y0 >= 0) & (y0 < Hn);
    bool vy1 = (y1 >= 0) & (y1 < Hn);
    bool vx0 = (x0 >= 0) & (x0 < Wn);
    bool vx1 = (x1 >= 0) & (x1 < Wn);
    int y0c = min(max(y0, 0), Hn - 1), y1c = min(max(y1, 0), Hn - 1);
    int x0c = min(max(x0, 0), Wn - 1), x1c = min(max(x1, 0), Wn - 1);

    int base = bi * HWn;
    float* s = &sampS[lp][k][0];
    ((int*)s)[0] = (base + y0c * Wn + x0c) * Cn;
    ((int*)s)[1] = (base + y0c * Wn + x1c) * Cn;
    ((int*)s)[2] = (base + y1c * Wn + x0c) * Cn;
    ((int*)s)[3] = (base + y1c * Wn + x1c) * Cn;
    s[4] = (vy0 && vx0) ? m * (1.f - wy) * (1.f - wx) : 0.f;
    s[5] = (vy0 && vx1) ? m * (1.f - wy) * wx : 0.f;
    s[6] = (vy1 && vx0) ? m * wy * (1.f - wx) : 0.f;
    s[7] = (vy1 && vx1) ? m * wy * wx : 0.f;
  }
  __syncthreads();

  // ================= phase 2: deformable main GEMM (M=32,N=256) ==========
  // N-split: wave w owns cols [w*32, w*32+32); B direct to regs, no dup.
  float bj[2];
#pragma unroll
  for (int j = 0; j < 2; ++j) bj[j] = bias[(wave * 2 + j) * 16 + col];

  floatx4 acc[2][2];
#pragma unroll
  for (int i = 0; i < 2; ++i)
#pragma unroll
    for (int j = 0; j < 2; ++j) acc[i][j] = (floatx4){0.f, 0.f, 0.f, 0.f};

  half8 g00, g01, g10, g11;
  half8 bwA[2][2], bwB[2][2];  // [kq][j], chunk-parity slots
  int4 ofsC = {0, 0, 0, 0}, ofsN = {0, 0, 0, 0};
  float4 wvC = {0.f, 0.f, 0.f, 0.f}, wvN = wvC;

  // prologue
  if (gth) {
    ofsC = *(const int4*)&sampS[ar][0][0];
    wvC = *(const float4*)&sampS[ar][0][4];
    ofsN = ofsC; wvN = wvC;
    g00 = *(const half8*)(xh + (size_t)ofsC.x + aci);
    g01 = *(const half8*)(xh + (size_t)ofsC.y + aci);
    g10 = *(const half8*)(xh + (size_t)ofsC.z + aci);
    g11 = *(const half8*)(xh + (size_t)ofsC.w + aci);
  }
#pragma unroll
  for (int kq = 0; kq < 2; ++kq)
#pragma unroll
    for (int j = 0; j < 2; ++j) {
      bwA[kq][j] = *(const half8*)(wtp +
          (size_t)((wave * 2 + j) * 2 + kq) * 512 + lane * 8);
      bwB[kq][j] = *(const half8*)(wtp + 16384 +
          (size_t)((wave * 2 + j) * 2 + kq) * 512 + lane * 8);
    }

#pragma unroll 1
  for (int t = 0; t < 9; ++t) {
    if (gth && t < 8) {
      ofsN = *(const int4*)&sampS[ar][t + 1][0];
      wvN = *(const float4*)&sampS[ar][t + 1][4];
    }
#pragma unroll
    for (int cc = 0; cc < 4; ++cc) {          // chunk c = 4t+cc; buf = cc&1
      // 1. stage A chunk c (gather role only; waits the 4 gather loads)
      if (gth) {
        _Float16 h00 = (_Float16)wvC.x, h01 = (_Float16)wvC.y;
        _Float16 h10 = (_Float16)wvC.z, h11 = (_Float16)wvC.w;
        half8 r;
#pragma unroll
        for (int e = 0; e < 8; ++e)
          r[e] = g00[e] * h00 + g01[e] * h01 + g10[e] * h10 + g11[e] * h11;
        *(half8*)&As[cc & 1][ar][aci] = r;
        // 2. issue gathers for chunk c+1 (stay in flight across barrier)
        if (cc < 3) {
          int ci = (cc + 1) * 64 + aci;
          g00 = *(const half8*)(xh + (size_t)ofsC.x + ci);
          g01 = *(const half8*)(xh + (size_t)ofsC.y + ci);
          g10 = *(const half8*)(xh + (size_t)ofsC.z + ci);
          g11 = *(const half8*)(xh + (size_t)ofsC.w + ci);
        } else if (t < 8) {
          g00 = *(const half8*)(xh + (size_t)ofsN.x + aci);
          g01 = *(const half8*)(xh + (size_t)ofsN.y + aci);
          g10 = *(const half8*)(xh + (size_t)ofsN.z + aci);
          g11 = *(const half8*)(xh + (size_t)ofsN.w + aci);
        }
      }

      __builtin_amdgcn_s_waitcnt(LGKM0);   // LDS visible; vmem stays outstanding
      __builtin_amdgcn_s_barrier();

      half8 af[2][2];
#pragma unroll
      for (int kq = 0; kq < 2; ++kq)
#pragma unroll
        for (int i = 0; i < 2; ++i)
          af[kq][i] =
              *(const half8*)&As[cc & 1][i * 16 + col][kq * 32 + quad * 8];

#pragma unroll
      for (int kq = 0; kq < 2; ++kq)
#pragma unroll
        for (int i = 0; i < 2; ++i)
#pragma unroll
          for (int j = 0; j < 2; ++j)
            acc[i][j] = __builtin_amdgcn_mfma_f32_16x16x32_f16(
                af[kq][i], (cc & 1) ? bwB[kq][j] : bwA[kq][j], acc[i][j], 0, 0, 0);

      // 3. refill just-consumed parity slot with chunk c+2 (after MFMA: WAR-safe)
      if (cc < 2 || t < 8) {
        const _Float16* wsrc = wtp + ((size_t)(4 * t) + cc + 2) * 16384;
#pragma unroll
        for (int kq = 0; kq < 2; ++kq)
#pragma unroll
          for (int j = 0; j < 2; ++j) {
            half8 v = *(const half8*)(wsrc +
                (size_t)((wave * 2 + j) * 2 + kq) * 512 + lane * 8);
            if (cc & 1) bwB[kq][j] = v; else bwA[kq][j] = v;
          }
      }
    }
    ofsC = ofsN;
    wvC = wvN;
  }

  // epilogue: bias + relu. Hidden layers: f16 NHWC. Last layer: fp32 NCHW.
#pragma unroll
  for (int i = 0; i < 2; ++i)
#pragma unroll
    for (int j = 0; j < 2; ++j) {
      int n = (wave * 2 + j) * 16 + col;
      if (outf) {
        int pb = p0 + i * 16 + quad * 4;
        int bi = pb >> 12;
        int pyx = pb & 4095;
        float4 v;
        v.x = fmaxf(acc[i][j][0] + bj[j], 0.f);
        v.y = fmaxf(acc[i][j][1] + bj[j], 0.f);
        v.z = fmaxf(acc[i][j][2] + bj[j], 0.f);
        v.w = fmaxf(acc[i][j][3] + bj[j], 0.f);
        *(float4*)(outf + ((size_t)(bi * On + n)) * HWn + pyx) = v;
      } else {
#pragma unroll
        for (int r = 0; r < 4; ++r) {
          int pp = p0 + i * 16 + quad * 4 + r;
          float v = fmaxf(acc[i][j][r] + bj[j], 0.f);
          outh[(size_t)pp * On + n] = (_Float16)v;
        }
      }
    }
}

// ---------------------------------------------------------------------------
extern "C" void kernel_launch(void* const* d_in, const int* in_sizes, int n_in,
                              void* d_out, int out_size, void* d_ws, size_t ws_size,
                              hipStream_t stream) {
  (void)in_sizes; (void)n_in; (void)out_size; (void)ws_size;
  const float* x = (const float*)d_in[0];

  _Float16* act0h = (_Float16*)d_ws;                     // Pn*Cn f16
  _Float16* act1h = act0h + (size_t)Pn * Cn;             // Pn*Cn f16
  _Float16* wbop  = act1h + (size_t)Pn * Cn;             // 3*36*2048 f16
  _Float16* wtp   = wbop + (size_t)3 * 36 * 2048;        // 3*256*Kc f16

  k_init<<<1888, 256, 0, stream>>>(
      x, act0h,
      (const float*)d_in[3], (const float*)d_in[7], (const float*)d_in[11],
      (const float*)d_in[1], (const float*)d_in[5], (const float*)d_in[9],
      wtp, wbop);

  _Float16* cur = act0h;
  _Float16* nxt = act1h;
  for (int l = 0; l < 3; ++l) {
    const float* b_off = (const float*)d_in[2 + l * 4];
    const float* b     = (const float*)d_in[4 + l * 4];
    k_layer<<<Pn / 32, 512, 0, stream>>>(
        cur, wbop + (size_t)l * 36 * 2048, b_off,
        wtp + (size_t)l * 256 * Kc, b, nxt,
        (l == 2) ? (float*)d_out : nullptr);
    _Float16* tswap = cur; cur = nxt; nxt = tswap;
  }
}

// Round 10
// 233.892 us; speedup vs baseline: 1.0486x; 1.0486x over previous
//
#include <hip/hip_runtime.h>
#include <math.h>

#define Bn 4
#define Cn 256
#define Hn 64
#define Wn 64
#define On 256
#define HWn 4096
#define Pn 16384   // B*H*W
#define Kc 2304    // 9*256

// s_waitcnt imm: vmcnt=63 (no wait), expcnt=7 (no wait), lgkmcnt=0 (drain LDS)
#define LGKM0 0xc07f

typedef _Float16 half8 __attribute__((ext_vector_type(8)));
typedef float floatx4 __attribute__((ext_vector_type(4)));

// ---------------------------------------------------------------------------
// R16 init kernel (unchanged; layouts bit-identical):
//  blocks 0..1023: fp32 NCHW -> f16 NHWC transpose; 1024..1791: main-weight
//  pack (half8 stores); 1792..1887: offset-weight pack (ch-group-major).
__global__ void k_init(const float* __restrict__ x, _Float16* __restrict__ act0,
                       const float* __restrict__ w0, const float* __restrict__ w1,
                       const float* __restrict__ w2, const float* __restrict__ wo0,
                       const float* __restrict__ wo1, const float* __restrict__ wo2,
                       _Float16* __restrict__ wtp, _Float16* __restrict__ wbop) {
  int bx = blockIdx.x;
  int tid = threadIdx.x;   // 0..255
  if (bx < 1024) {
    __shared__ float Tf[64][65];
    int b = bx >> 8;
    int c0 = ((bx >> 6) & 3) << 6;
    int hw0 = (bx & 63) << 6;
    const float* ib = x + ((size_t)b * Cn + c0) * HWn + hw0;
    _Float16* ob = act0 + ((size_t)b * HWn + hw0) * Cn + c0;
    int ty = tid >> 4, tx = tid & 15;
#pragma unroll
    for (int p = 0; p < 4; ++p) {
      int ch = p * 16 + ty;
      float4 v = *(const float4*)(ib + (size_t)ch * HWn + tx * 4);
      Tf[ch][tx * 4 + 0] = v.x;
      Tf[ch][tx * 4 + 1] = v.y;
      Tf[ch][tx * 4 + 2] = v.z;
      Tf[ch][tx * 4 + 3] = v.w;
    }
    __syncthreads();
    int hwR = tid >> 3, seg = tid & 7;
#pragma unroll
    for (int p = 0; p < 2; ++p) {
      int hw = p * 32 + hwR;
      half8 h;
#pragma unroll
      for (int k = 0; k < 8; ++k) h[k] = (_Float16)Tf[seg * 8 + k][hw];
      *(half8*)(ob + (size_t)hw * Cn + seg * 8) = h;
    }
  } else if (bx < 1792) {
    int b2 = bx - 1024;
    int l = b2 >> 8;
    int n = b2 & 255;
    const float* w = (l == 0) ? w0 : (l == 1) ? w1 : w2;
    _Float16* dst = wtp + (size_t)l * 256 * Kc;
    int g = n >> 4, col = n & 15;
#pragma unroll
    for (int e2 = tid; e2 < 288; e2 += 256) {
      int c = e2 >> 3;          // 0..35
      int r = e2 & 7;
      int kq = r >> 2;
      int quad = r & 3;
      int t = c >> 2;
      int cq = c & 3;
      const float* s = w + (size_t)n * 2304 + (size_t)(cq * 64 + kq * 32 + quad * 8) * 9 + t;
      half8 h;
#pragma unroll
      for (int e = 0; e < 8; ++e) h[e] = (_Float16)s[e * 9];
      *(half8*)(dst + ((size_t)((c * 16 + g) * 2 + kq)) * 512 + (quad * 16 + col) * 8) = h;
    }
  } else {
    int b3 = bx - 1792;
    int l = b3 >> 5;
    int n = b3 & 31;
    const float* w = (l == 0) ? wo0 : (l == 1) ? wo1 : wo2;
    _Float16* dst = wbop + (size_t)l * 36 * 2048;
    int g = n >> 4, col = n & 15;
#pragma unroll
    for (int e2 = tid; e2 < 288; e2 += 256) {
      int c = e2 >> 3;
      int r = e2 & 7;
      int kq = r >> 2;
      int quad = r & 3;
      int cw = c / 9;
      int t = c - cw * 9;
      half8 h;
      if (n < 27) {
        const float* s = w + ((size_t)n * 256 + cw * 64 + kq * 32 + quad * 8) * 9 + t;
#pragma unroll
        for (int e = 0; e < 8; ++e) h[e] = (_Float16)s[e * 9];
      } else {
#pragma unroll
        for (int e = 0; e < 8; ++e) h[e] = (_Float16)0.f;
      }
      *(half8*)(dst + ((size_t)((c * 2 + g) * 2 + kq)) * 512 + (quad * 16 + col) * 8) = h;
    }
  }
}

// ---------------------------------------------------------------------------
// R18 layer kernel = R8 verbatim EXCEPT phase-2 gather pipeline deepened to
// DEPTH-2 (the single change). Diagnosis: combined model
//   chunk_time = max(L2-BW time, exposed gather latency) + barrier cost;
// R2/R9 at 96KB/chunk are BW-pinned (~1714cy); R3/R5 at 64KB/chunk have a
// ~1150cy BW floor but measure 1700-1900 -> ~550cy of EXPOSED issue-to-use
// latency on the gather path, which was depth-1 in every round (only the
// MFMA cluster ~350cy of slack vs loaded-L2 latency ~1000cy). B path is
// depth-2 already. Now gathers for chunk c+2 issue at chunk c into parity
// register sets gEv/gOd (+16 VGPR), giving >=2 chunks (~2400cy) of slack.
// Phase 1 (LDS window), Bs staging, barriers, XCD swizzle: unchanged.
__global__ __launch_bounds__(512) void k_layer(
    const _Float16* __restrict__ xh,
    const _Float16* __restrict__ wbop, const float* __restrict__ boff,
    const _Float16* __restrict__ wtp, const float* __restrict__ bias,
    _Float16* __restrict__ outh, float* __restrict__ outf) {
  __shared__ __align__(16) _Float16 As[2][64][72];    // 18.4 KB
  __shared__ __align__(16) _Float16 Bs[2][16384];     // 64 KB
  __shared__ __align__(16) _Float16 win[3 * 66 * 64]; // 25.3 KB
  __shared__ __align__(16) float omS[64 * 33];        // 8.4 KB
  __shared__ __align__(16) float sampS[64][9][8];     // 18 KB

  int bid = blockIdx.x;
  int lb = ((bid & 7) << 5) + (bid >> 3);   // XCD-contiguous logical block
  int p0 = lb * 64;
  int tid = threadIdx.x;       // 0..511
  int lane = tid & 63;
  int wave = tid >> 6;         // 0..7
  int quad = lane >> 4;
  int col = lane & 15;

  int ar = tid >> 3;           // staging/gather row 0..63
  int aci = (tid & 7) * 8;     // 8-channel segment

  int yB = (p0 & 4095) >> 6;   // block-uniform: tile is one full image row
  int bB = p0 >> 12;

  half8 zero8;
#pragma unroll
  for (int e = 0; e < 8; ++e) zero8[e] = (_Float16)0.f;

  // ================= phase 1: offset conv (window sweep) ================
  int mi = wave >> 1;   // 0..3 (16-row group)
  int ng = wave & 1;    // 0..1 (16-col group)

  floatx4 acc1 = (floatx4){0.f, 0.f, 0.f, 0.f};
  half8 boA[2], boB[2];
#pragma unroll
  for (int kq = 0; kq < 2; ++kq) {
    boA[kq] = *(const half8*)(wbop + (size_t)(ng * 2 + kq) * 512 + lane * 8);
    boB[kq] = *(const half8*)(wbop + 2048 + (size_t)(ng * 2 + kq) * 512 + lane * 8);
  }

#pragma unroll 1
  for (int cg = 0; cg < 4; ++cg) {
    for (int e = tid; e < 1584; e += 512) {
      int seg = e & 7;
      int rowpx = e >> 3;          // 0..197
      int r = rowpx / 66;          // 0..2
      int px = rowpx - r * 66;     // 0..65
      int yy = yB + r - 1;
      int xx = px - 1;
      half8 v = zero8;
      if (((unsigned)yy < 64u) & ((unsigned)xx < 64u))
        v = *(const half8*)(xh + ((size_t)((bB * Hn + yy) * Wn + xx)) * Cn +
                            cg * 64 + seg * 8);
      int ba = (rowpx * 128 + seg * 16) ^ ((px & 7) << 4);
      *(half8*)((char*)win + ba) = v;
    }
    __syncthreads();

#pragma unroll
    for (int t = 0; t < 9; ++t) {
      int cp = cg * 9 + t;
      int dty = t / 3;
      int dtx = t % 3;
#pragma unroll
      for (int kq = 0; kq < 2; ++kq) {
        int pxw = mi * 16 + col + dtx;   // 0..65
        int ba = ((dty * 66 + pxw) * 128 + kq * 64 + quad * 16) ^ ((pxw & 7) << 4);
        half8 af = *(const half8*)((const char*)win + ba);
        acc1 = __builtin_amdgcn_mfma_f32_16x16x32_f16(
            af, (cp & 1) ? boB[kq] : boA[kq], acc1, 0, 0, 0);
      }
      if (cp + 2 < 36) {
        const _Float16* wob = wbop + (size_t)(cp + 2) * 2048;
#pragma unroll
        for (int kq = 0; kq < 2; ++kq) {
          half8 v2 = *(const half8*)(wob + (size_t)(ng * 2 + kq) * 512 + lane * 8);
          if (cp & 1) boB[kq] = v2; else boA[kq] = v2;
        }
      }
    }
    __syncthreads();
  }

  // om -> LDS
  {
    int n1 = ng * 16 + col;
    if (n1 < 27) {
      float bb = boff[n1];
#pragma unroll
      for (int r = 0; r < 4; ++r)
        omS[(mi * 16 + quad * 4 + r) * 33 + n1] = acc1[r] + bb;
    }
  }
  __syncthreads();

  // fused coords: 64 px x 9 taps = 576 entries -> sampS (LDS)
  for (int e = tid; e < 576; e += 512) {
    int lp = e / 9;
    int k = e - lp * 9;
    int pp = p0 + lp;
    int bi = pp >> 12;
    int pyx = pp & 4095;
    int py = pyx >> 6, px = pyx & 63;

    float dy = omS[lp * 33 + 2 * k];
    float dx = omS[lp * 33 + 2 * k + 1];
    float m = 1.f / (1.f + expf(-omS[lp * 33 + 18 + k]));

    float ys = (float)(py + k / 3 - 1) + dy;
    float xs = (float)(px + k % 3 - 1) + dx;
    float y0f = floorf(ys), x0f = floorf(xs);
    float wy = ys - y0f, wx = xs - x0f;
    int y0 = (int)y0f, x0 = (int)x0f;
    int y1 = y0 + 1, x1 = x0 + 1;

    bool vy0 = (y0 >= 0) & (y0 < Hn);
    bool vy1 = (y1 >= 0) & (y1 < Hn);
    bool vx0 = (x0 >= 0) & (x0 < Wn);
    bool vx1 = (x1 >= 0) & (x1 < Wn);
    int y0c = min(max(y0, 0), Hn - 1), y1c = min(max(y1, 0), Hn - 1);
    int x0c = min(max(x0, 0), Wn - 1), x1c = min(max(x1, 0), Wn - 1);

    int base = bi * HWn;
    float* s = &sampS[lp][k][0];
    ((int*)s)[0] = (base + y0c * Wn + x0c) * Cn;
    ((int*)s)[1] = (base + y0c * Wn + x1c) * Cn;
    ((int*)s)[2] = (base + y1c * Wn + x0c) * Cn;
    ((int*)s)[3] = (base + y1c * Wn + x1c) * Cn;
    s[4] = (vy0 && vx0) ? m * (1.f - wy) * (1.f - wx) : 0.f;
    s[5] = (vy0 && vx1) ? m * (1.f - wy) * wx : 0.f;
    s[6] = (vy1 && vx0) ? m * wy * (1.f - wx) : 0.f;
    s[7] = (vy1 && vx1) ? m * wy * wx : 0.f;
  }
  __syncthreads();

  // ================= phase 2: deformable main GEMM (M=64,N=256) ==========
  int mw = wave >> 2;          // 0..1 (32-row half)
  int nw = wave & 3;           // 0..3 (64-col group)

  float bj[4];
#pragma unroll
  for (int j = 0; j < 4; ++j) bj[j] = bias[(nw * 4 + j) * 16 + col];

  floatx4 acc[2][4];
#pragma unroll
  for (int i = 0; i < 2; ++i)
#pragma unroll
    for (int j = 0; j < 4; ++j) acc[i][j] = (floatx4){0.f, 0.f, 0.f, 0.f};

  half8 gEv[4], gOd[4];        // gather regs, chunk-parity sets (DEPTH-2)
  half8 bst0[4], bst1[4];      // B staging regs, chunk-parity slots (depth-2)
  int4 ofsC, ofsN;
  float4 wvC, wvN;

  // prologue: tap0 samp; gathers for chunk 0 (even) AND chunk 1 (odd);
  // B chunks 0 and 1 into regs.
  ofsC = *(const int4*)&sampS[ar][0][0];
  wvC = *(const float4*)&sampS[ar][0][4];
  ofsN = ofsC; wvN = wvC;
  gEv[0] = *(const half8*)(xh + (size_t)ofsC.x + aci);
  gEv[1] = *(const half8*)(xh + (size_t)ofsC.y + aci);
  gEv[2] = *(const half8*)(xh + (size_t)ofsC.z + aci);
  gEv[3] = *(const half8*)(xh + (size_t)ofsC.w + aci);
  gOd[0] = *(const half8*)(xh + (size_t)ofsC.x + 64 + aci);
  gOd[1] = *(const half8*)(xh + (size_t)ofsC.y + 64 + aci);
  gOd[2] = *(const half8*)(xh + (size_t)ofsC.z + 64 + aci);
  gOd[3] = *(const half8*)(xh + (size_t)ofsC.w + 64 + aci);
#pragma unroll
  for (int q = 0; q < 4; ++q)
    bst0[q] = *(const half8*)(wtp + (size_t)(q * 512 + tid) * 8);
#pragma unroll
  for (int q = 0; q < 4; ++q)
    bst1[q] = *(const half8*)(wtp + 16384 + (size_t)(q * 512 + tid) * 8);

#pragma unroll 1
  for (int t = 0; t < 9; ++t) {
    if (t < 8) {
      ofsN = *(const int4*)&sampS[ar][t + 1][0];
      wvN = *(const float4*)&sampS[ar][t + 1][4];
    }
#pragma unroll
    for (int cc = 0; cc < 4; ++cc) {          // chunk c = 4t+cc; buf = cc&1
      // 1. stage A chunk c from parity regs (issued at c-2: >=2 chunks slack)
      {
        _Float16 h00 = (_Float16)wvC.x, h01 = (_Float16)wvC.y;
        _Float16 h10 = (_Float16)wvC.z, h11 = (_Float16)wvC.w;
        half8 r;
        if (cc & 1) {
#pragma unroll
          for (int e = 0; e < 8; ++e)
            r[e] = gOd[0][e] * h00 + gOd[1][e] * h01 + gOd[2][e] * h10 + gOd[3][e] * h11;
        } else {
#pragma unroll
          for (int e = 0; e < 8; ++e)
            r[e] = gEv[0][e] * h00 + gEv[1][e] * h01 + gEv[2][e] * h10 + gEv[3][e] * h11;
        }
        *(half8*)&As[cc & 1][ar][aci] = r;
      }
      // 2. stage B chunk c from reg slots (loaded at c-2; no vm wait)
#pragma unroll
      for (int q = 0; q < 4; ++q)
        *(half8*)&Bs[cc & 1][(q * 512 + tid) * 8] = (cc & 1) ? bst1[q] : bst0[q];
      // 3. issue gathers for chunk c+2 into the just-consumed parity set.
      //    tap(c+2) = t for cc<2 (ofsC), t+1 for cc>=2 (ofsN).
      if (4 * t + cc + 2 <= 35) {
        int4 o2 = (cc < 2) ? ofsC : ofsN;
        int ci2 = ((cc + 2) & 3) * 64 + aci;
        if (cc & 1) {
          gOd[0] = *(const half8*)(xh + (size_t)o2.x + ci2);
          gOd[1] = *(const half8*)(xh + (size_t)o2.y + ci2);
          gOd[2] = *(const half8*)(xh + (size_t)o2.z + ci2);
          gOd[3] = *(const half8*)(xh + (size_t)o2.w + ci2);
        } else {
          gEv[0] = *(const half8*)(xh + (size_t)o2.x + ci2);
          gEv[1] = *(const half8*)(xh + (size_t)o2.y + ci2);
          gEv[2] = *(const half8*)(xh + (size_t)o2.z + ci2);
          gEv[3] = *(const half8*)(xh + (size_t)o2.w + ci2);
        }
      }
      // 4. refill B slot with chunk c+2 (exists iff 4t+cc+2 <= 35)
      if (cc < 2 || t < 8) {
        const _Float16* wsrc = wtp + ((size_t)(4 * t) + cc + 2) * 16384;
#pragma unroll
        for (int q = 0; q < 4; ++q) {
          half8 v = *(const half8*)(wsrc + (size_t)(q * 512 + tid) * 8);
          if (cc & 1) bst1[q] = v; else bst0[q] = v;
        }
      }

      __builtin_amdgcn_s_waitcnt(LGKM0);   // LDS visible; vmem stays outstanding
      __builtin_amdgcn_s_barrier();

      half8 af[2][2];
#pragma unroll
      for (int kq = 0; kq < 2; ++kq)
#pragma unroll
        for (int i = 0; i < 2; ++i)
          af[kq][i] =
              *(const half8*)&As[cc & 1][mw * 32 + i * 16 + col][kq * 32 + quad * 8];

      half8 bf[2][4];
#pragma unroll
      for (int kq = 0; kq < 2; ++kq)
#pragma unroll
        for (int j = 0; j < 4; ++j)
          bf[kq][j] =
              *(const half8*)&Bs[cc & 1][((nw * 4 + j) * 2 + kq) * 512 + lane * 8];

#pragma unroll
      for (int kq = 0; kq < 2; ++kq)
#pragma unroll
        for (int i = 0; i < 2; ++i)
#pragma unroll
          for (int j = 0; j < 4; ++j)
            acc[i][j] = __builtin_amdgcn_mfma_f32_16x16x32_f16(
                af[kq][i], bf[kq][j], acc[i][j], 0, 0, 0);
    }
    ofsC = ofsN;
    wvC = wvN;
  }

  // epilogue: bias + relu. Hidden layers: f16 NHWC. Last layer: fp32 NCHW.
#pragma unroll
  for (int i = 0; i < 2; ++i)
#pragma unroll
    for (int j = 0; j < 4; ++j) {
      int n = (nw * 4 + j) * 16 + col;
      if (outf) {
        int pb = p0 + mw * 32 + i * 16 + quad * 4;
        int bi = pb >> 12;
        int pyx = pb & 4095;
        float4 v;
        v.x = fmaxf(acc[i][j][0] + bj[j], 0.f);
        v.y = fmaxf(acc[i][j][1] + bj[j], 0.f);
        v.z = fmaxf(acc[i][j][2] + bj[j], 0.f);
        v.w = fmaxf(acc[i][j][3] + bj[j], 0.f);
        *(float4*)(outf + ((size_t)(bi * On + n)) * HWn + pyx) = v;
      } else {
#pragma unroll
        for (int r = 0; r < 4; ++r) {
          int pp = p0 + mw * 32 + i * 16 + quad * 4 + r;
          float v = fmaxf(acc[i][j][r] + bj[j], 0.f);
          outh[(size_t)pp * On + n] = (_Float16)v;
        }
      }
    }
}

// ---------------------------------------------------------------------------
extern "C" void kernel_launch(void* const* d_in, const int* in_sizes, int n_in,
                              void* d_out, int out_size, void* d_ws, size_t ws_size,
                              hipStream_t stream) {
  (void)in_sizes; (void)n_in; (void)out_size; (void)ws_size;
  const float* x = (const float*)d_in[0];

  _Float16* act0h = (_Float16*)d_ws;                     // Pn*Cn f16
  _Float16* act1h = act0h + (size_t)Pn * Cn;             // Pn*Cn f16
  _Float16* wbop  = act1h + (size_t)Pn * Cn;             // 3*36*2048 f16
  _Float16* wtp   = wbop + (size_t)3 * 36 * 2048;        // 3*256*Kc f16

  k_init<<<1888, 256, 0, stream>>>(
      x, act0h,
      (const float*)d_in[3], (const float*)d_in[7], (const float*)d_in[11],
      (const float*)d_in[1], (const float*)d_in[5], (const float*)d_in[9],
      wtp, wbop);

  _Float16* cur = act0h;
  _Float16* nxt = act1h;
  for (int l = 0; l < 3; ++l) {
    const float* b_off = (const float*)d_in[2 + l * 4];
    const float* b     = (const float*)d_in[4 + l * 4];
    k_layer<<<Pn / 64, 512, 0, stream>>>(
        cur, wbop + (size_t)l * 36 * 2048, b_off,
        wtp + (size_t)l * 256 * Kc, b, nxt,
        (l == 2) ? (float*)d_out : nullptr);
    _Float16* tswap = cur; cur = nxt; nxt = tswap;
  }
}